// Round 15
// baseline (205.210 us; speedup 1.0000x reference)
//
#include <hip/hip_runtime.h>
#include <hip/hip_bf16.h>
#include <math.h>
#include <stdint.h>
#include <string.h>

#define BB 8
#define SS 96
#define DD 768
#define RR 24
#define RSEQ 8
#define TAG 3
#define D3 2304   // 3*D
#define NC 72     // R*TAG

typedef __attribute__((ext_vector_type(8))) short bf16x8;
typedef __attribute__((ext_vector_type(4))) float f32x4;
typedef _Float16 f16x8 __attribute__((ext_vector_type(8)));
typedef _Float16 f16x2 __attribute__((ext_vector_type(2)));

// async global->LDS, 16 B/lane; LDS dest = wave-uniform base + lane*16.
typedef __attribute__((address_space(3))) uint8_t lds_u8;
typedef const __attribute__((address_space(1))) uint8_t glb_u8;
static __device__ __forceinline__ void glld16(const void* g, void* l) {
  __builtin_amdgcn_global_load_lds((glb_u8*)g, (lds_u8*)l, 16, 0, 0);
}

#define VMW(N) asm volatile("s_waitcnt vmcnt(" #N ")" ::: "memory")

// round-half-up f32 pair -> packed bf16x2: add,add,v_perm = 3 VALU.
static __device__ inline uint32_t pkrhu(float lo, float hi) {
  uint32_t a, b;
  memcpy(&a, &lo, 4);
  memcpy(&b, &hi, 4);
  return __builtin_amdgcn_perm(b + 0x8000u, a + 0x8000u, 0x07060302u);
}
static __device__ inline uint32_t pkrne(float lo, float hi) {
  uint32_t a, b;
  memcpy(&a, &lo, 4);
  memcpy(&b, &hi, 4);
  a += 0x7FFFu + ((a >> 16) & 1u);
  b += 0x7FFFu + ((b >> 16) & 1u);
  return (a >> 16) | (b & 0xFFFF0000u);
}
// f32 pair -> packed f16x2 (v_cvt_f16_f32 x2 + pack)
static __device__ inline uint32_t pkf16(float lo, float hi) {
  union { f16x2 h; uint32_t u; } r;
  r.h[0] = (_Float16)lo;
  r.h[1] = (_Float16)hi;
  return r.u;
}
static __device__ inline uint16_t f16b(float v) {
  union { _Float16 h; uint16_t u; } r;
  r.h = (_Float16)v;
  return r.u;
}

// ---------------------------------------------------------------------------
// Kernel 0 (shrunk): SG k-split partial dots only (atomicAdd into pre-zeroed
// SG). grid 128 = 8 samples x 16 d-chunks of 48.
// ---------------------------------------------------------------------------
__global__ __launch_bounds__(256) void k_prepSG(const float* __restrict__ enc,
                                                const float* __restrict__ rel,
                                                float* __restrict__ SG) {
  __shared__ __align__(16) float AsF[RSEQ][48];  // 1.5 KB
  const int idx = blockIdx.x;
  const int t = threadIdx.x;
  const int b = idx >> 4;
  const int d0 = (idx & 15) * 48;

  if (t < 96) {
    const int r = t / 12, q4 = (t % 12) * 4;
    *(float4*)&AsF[r][q4] = *(const float4*)&rel[((size_t)b * RSEQ + r) * DD + d0 + q4];
  }
  __syncthreads();

  for (int e = t; e < RSEQ * (SS + RSEQ); e += 256) {
    const int r = e & 7, s = e >> 3;
    const float* row = (s < SS) ? (enc + ((size_t)b * SS + s) * DD + d0) : &AsF[s - SS][0];
    float a0 = 0.f, a1 = 0.f, a2 = 0.f, a3 = 0.f;
#pragma unroll
    for (int d = 0; d < 48; d += 4) {
      const float4 rv = *(const float4*)&row[d];
      a0 += AsF[r][d + 0] * rv.x;
      a1 += AsF[r][d + 1] * rv.y;
      a2 += AsF[r][d + 2] * rv.z;
      a3 += AsF[r][d + 3] * rv.w;
    }
    atomicAdd(&SG[((size_t)b * RSEQ + r) * 104 + s], (a0 + a1) + (a2 + a3));
  }
}

// ---------------------------------------------------------------------------
// Kernel 1 (fused): blocks 0..7 = refine serial core + refB epilogue for the
// whole sample (P stays in LDS — no Pst round trip); blocks 8..43 = Wb prep
// (rel_W^T -> f16); blocks 44..907 = Tp transpose (proj_W^T -> bf16).
// The prep blocks run on the CUs that the 8 refine blocks leave idle,
// hiding the transpose entirely behind the 24-step serial refine.
// grid 908 x 256.
// ---------------------------------------------------------------------------
__global__ __launch_bounds__(256) void k_refR(const float* __restrict__ SG,
                                              const float* __restrict__ enc,
                                              const float* __restrict__ rel,
                                              const float* __restrict__ relW,
                                              uint16_t* __restrict__ Wb,
                                              const float* __restrict__ projW,
                                              uint16_t* __restrict__ Tp,
                                              uint16_t* __restrict__ encRb) {
  __shared__ __align__(16) char smem[34176];
  const int blk = blockIdx.x;
  const int t = threadIdx.x;

  if (blk < 8) {
    // ---- refine core (round-8 proven version) + fused refB epilogue ----
    const int b = blk;
    float (*S0)[SS] = (float(*)[SS])smem;                    // 3072 B
    float (*G)[RSEQ] = (float(*)[RSEQ])(smem + 3072);        // 256 B
    float (*P)[SS] = (float(*)[SS])(smem + 3328);            // 3072 B
    float (*sc)[SS] = (float(*)[SS])(smem + 6400);           // 3072 B
    float (*As)[DD + 4] = (float(*)[DD + 4])(smem + 9472);   // 24704 B
    const float scale = 0.036084391824351613f;  // 1/sqrt(768)

    for (int e = t; e < RSEQ * 104; e += 256) {
      const int r = e / 104, c = e % 104;
      const float v = SG[(size_t)b * RSEQ * 104 + e];
      if (c < SS) S0[r][c] = v;
      else G[r][c - SS] = v;
    }
    for (int e = t; e < RSEQ * SS; e += 256) ((float*)P)[e] = 0.f;
    __syncthreads();

    const int wave = t >> 6, lane = t & 63;
    for (int step = 0; step < RR; ++step) {
      for (int e = t; e < RSEQ * SS; e += 256) {
        const int r = e / SS, s = e % SS;
        float acc = S0[r][s];
#pragma unroll
        for (int r2 = 0; r2 < RSEQ; ++r2) acc += G[r][r2] * P[r2][s];
        sc[r][s] = acc * scale;
      }
      __syncthreads();
#pragma unroll
      for (int rr = 0; rr < 2; ++rr) {
        const int r = wave * 2 + rr;
        const float m1 = sc[r][lane];
        const float m2 = (lane < 32) ? sc[r][lane + 64] : -1e30f;
        float mx = fmaxf(m1, m2);
#pragma unroll
        for (int o = 32; o > 0; o >>= 1) mx = fmaxf(mx, __shfl_xor(mx, o, 64));
        const float e1 = __expf(m1 - mx);
        const float e2 = (lane < 32) ? __expf(m2 - mx) : 0.f;
        float sm = e1 + e2;
#pragma unroll
        for (int o = 32; o > 0; o >>= 1) sm += __shfl_xor(sm, o, 64);
        const float inv = 1.f / sm;
        P[r][lane] += e1 * inv;
        if (lane < 32) P[r][lane + 64] += e2 * inv;
      }
      __syncthreads();
    }

    // ---- fused refB: enc' bf16 = enc + P^T @ A for the whole sample ----
    const float* Ag = rel + (size_t)b * RSEQ * DD;
    for (int e = t; e < RSEQ * DD / 4; e += 256) {
      const int r = (e * 4) / DD, d = (e * 4) % DD;
      *(float4*)&As[r][d] = *(const float4*)&Ag[e * 4];
    }
    __syncthreads();

    const float* Eb = enc + (size_t)b * SS * DD;
    uint16_t* Ob = encRb + (size_t)b * SS * DD;
    for (int e = t; e < SS * DD / 4; e += 256) {
      const int s = (e * 4) / DD, d = (e * 4) % DD;
      float4 v = ((const float4*)Eb)[e];
#pragma unroll
      for (int r = 0; r < RSEQ; ++r) {
        const float p = P[r][s];
        v.x += p * As[r][d + 0];
        v.y += p * As[r][d + 1];
        v.z += p * As[r][d + 2];
        v.w += p * As[r][d + 3];
      }
      uint2 w;
      w.x = pkrhu(v.x, v.y);
      w.y = pkrhu(v.z, v.w);
      *(uint2*)&Ob[e * 4] = w;
    }
  } else if (blk < 44) {
    // ---- Wb[96][2304] f16 = rel_W^T (rows 72..79 zero; 80..95 untouched) ----
    float* tile = (float*)smem;  // 64*72 f32 = 18432 B
    const int k0 = (blk - 8) * 64;
    const float* src = relW + (size_t)k0 * NC;
    for (int e = t; e < 64 * NC / 4; e += 256) ((float4*)tile)[e] = ((const float4*)src)[e];
    __syncthreads();
    for (int u = t; u < 80 * 16; u += 256) {
      const int n = u >> 4, kq = (u & 15) * 4;
      uint2 w = {0u, 0u};
      if (n < NC) {
        w.x = pkf16(tile[(kq + 0) * NC + n], tile[(kq + 1) * NC + n]);
        w.y = pkf16(tile[(kq + 2) * NC + n], tile[(kq + 3) * NC + n]);
      }
      *(uint2*)&Wb[(size_t)n * D3 + k0 + kq] = w;
    }
  } else {
    // ---- Tp[2304][1536] bf16 = proj_W^T, 64x64 tile ----
    const int bx = blk - 44;
    float (*tile)[65] = (float(*)[65])smem;  // 16640 B
    const int c0 = (bx % 36) * 64;
    const int r0 = (bx / 36) * 64;
    {
      const int tr = t >> 4;
      const int tc4 = (t & 15) * 4;
#pragma unroll
      for (int p = 0; p < 4; ++p) {
        const int r = tr + p * 16;
        const float4 v = *(const float4*)&projW[(size_t)(r0 + r) * D3 + c0 + tc4];
        tile[r][tc4 + 0] = v.x;
        tile[r][tc4 + 1] = v.y;
        tile[r][tc4 + 2] = v.z;
        tile[r][tc4 + 3] = v.w;
      }
    }
    __syncthreads();
    {
      const int cc = t >> 4;
      const int rr4 = (t & 15) * 4;
#pragma unroll
      for (int p = 0; p < 4; ++p) {
        const int c = cc + p * 16;
        uint2 w;
        w.x = pkrne(tile[rr4 + 0][c], tile[rr4 + 1][c]);
        w.y = pkrne(tile[rr4 + 2][c], tile[rr4 + 3][c]);
        *(uint2*)&Tp[(size_t)(c0 + c) * (2 * DD) + r0 + rr4] = w;
      }
    }
  }
}

// ---------------------------------------------------------------------------
// Kernel 2 v2: projection GEMM — 128x64 tiles: reads/MFMA 0.75, 432 blocks.
// glld16 2-barrier schedule. LDS 27648 B -> 4 blocks/CU. grid (6,72).
// ---------------------------------------------------------------------------
__global__ __launch_bounds__(256, 4) void k_proj(const uint16_t* __restrict__ Ab,
                                                 const uint16_t* __restrict__ Bt,
                                                 const float* __restrict__ pb,
                                                 uint16_t* __restrict__ Hh16,
                                                 uint16_t* __restrict__ Htf) {
  const int m0 = blockIdx.x * 128;
  const int gn0 = blockIdx.y * 64;
  const bool isH = gn0 < D3;               // uniform per block
  const int n0 = isH ? gn0 : gn0 - D3;
  const int halfk = isH ? 0 : DD;
  const int t = threadIdx.x, w = t >> 6, lane = t & 63;
  const int wm = w >> 1, wn = w & 1;
  const int lm = lane & 15, q = lane >> 4;

  __shared__ __align__(16) uint16_t As[128 * 72];  // 18432 B (18 issues)
  __shared__ __align__(16) uint16_t Bs[64 * 72];   //  9216 B (9 issues)

  const char* rp[7];
  char* lp[7];
#pragma unroll
  for (int r = 0; r < 7; ++r) {
    const int idx = w + 4 * r;
    rp[r] = nullptr;
    lp[r] = nullptr;
    if (idx < 27) {
      const int ii = (idx < 18) ? idx : idx - 18;
      const int beta = ii * 1024 + lane * 16;
      const int elem = beta >> 1;
      const int row = elem / 72;
      int o = elem - row * 72;
      if (o >= 64) o = 0;  // pad lanes: safe addr, land in LDS row pad
      if (idx < 18) {
        rp[r] = (const char*)(Ab + (size_t)(m0 + row) * DD + o);
        lp[r] = (char*)As + ii * 1024;
      } else {
        rp[r] = (const char*)(Bt + (size_t)(n0 + row) * (2 * DD) + halfk + o);
        lp[r] = (char*)Bs + ii * 1024;
      }
    }
  }

  f32x4 acc[4][2];
#pragma unroll
  for (int a = 0; a < 4; ++a)
#pragma unroll
    for (int c = 0; c < 2; ++c) acc[a][c] = (f32x4){0.f, 0.f, 0.f, 0.f};

  for (int k0 = 0; k0 < DD; k0 += 64) {
    __syncthreads();
#pragma unroll
    for (int r = 0; r < 7; ++r)
      if (rp[r]) glld16(rp[r] + 2 * k0, lp[r]);
    __syncthreads();
#pragma unroll
    for (int kk = 0; kk < 2; ++kk) {
      const int ko = kk * 32 + q * 8;
      bf16x8 af[4], bf[2];
#pragma unroll
      for (int mt = 0; mt < 4; ++mt)
        af[mt] = *(const bf16x8*)&As[(wm * 64 + mt * 16 + lm) * 72 + ko];
#pragma unroll
      for (int nt = 0; nt < 2; ++nt)
        bf[nt] = *(const bf16x8*)&Bs[(wn * 32 + nt * 16 + lm) * 72 + ko];
#pragma unroll
      for (int nt = 0; nt < 2; ++nt)
#pragma unroll
        for (int mt = 0; mt < 4; ++mt)
          acc[mt][nt] = __builtin_amdgcn_mfma_f32_16x16x32_bf16(af[mt], bf[nt], acc[mt][nt], 0, 0, 0);
    }
  }

#pragma unroll
  for (int nt = 0; nt < 2; ++nt) {
    const int ncol = n0 + wn * 32 + nt * 16 + lm;
    const int mrow = m0 + wm * 64 + q * 4;
    uint16_t* dst = isH ? Hh16 : Htf;
    const float bias = isH ? pb[ncol] : 0.f;
#pragma unroll
    for (int mt = 0; mt < 4; ++mt)
#pragma unroll
      for (int r = 0; r < 4; ++r)
        dst[(size_t)(mrow + mt * 16 + r) * D3 + ncol] = f16b(acc[mt][nt][r] + bias);
  }
}

// ---------------------------------------------------------------------------
// Kernel 3: pairwise GEMM v14 (frozen) — 12 waves = (iw x jh x kh); wave does
// full 48x80 tile of its i for its K=64 half of each 128-K phase; wave pairs
// reduce acc at the end through dead Stg. 3 pair-bufs, issue-after-barrier,
// counted vmcnt 4/2, XOR-swizzle, wrap prefetch, LDS 150528 -> 1 block/CU.
// grid 256, 768 threads.
// ---------------------------------------------------------------------------
#define HT_LDS 12288                     // 96 rows x 128 B
#define CH_B 22528                       // one chunk: 22 issues x 1024
#define NISS 22
#define NKC 36                           // K chunks of 64
#define NPH 18                           // phases of 2 chunks

__global__ __launch_bounds__(768, 1) void k_pairs(const uint16_t* __restrict__ Hh,
                                                  const uint16_t* __restrict__ Htb,
                                                  const uint16_t* __restrict__ Wb,
                                                  const float* __restrict__ relb,
                                                  float* __restrict__ out) {
  const int blk = blockIdx.x;
  const int b = blk >> 5, ii = blk & 31;
  const int t = threadIdx.x;
  const int w = t >> 6, lane = t & 63;
  const int lm = lane & 15, q = lane >> 4;
  const int iw = w >> 2;            // which of the 3 i's
  const int jh = (w >> 1) & 1;      // j-half (48 rows)
  const int kh = w & 1;             // K-half of each phase
  const int i = ii * 3 + iw;

  __shared__ __align__(16) uint16_t Hr[7680];             // 15360 B
  __shared__ __align__(16) uint16_t Stg[3][CH_B];         // 3 pair-bufs x 45056 B

  // ---- one-time: stage the 3 Hh rows (linear; issue idx 13 runs 512 B past
  //      the 3 rows — covered by Hh's slack) ----
  {
    const char* hh = (const char*)(Hh + ((size_t)b * SS + ii * 3) * D3);
#pragma unroll
    for (int r = 0; r < 2; ++r) {
      const int idx = w + 12 * r;
      if (idx < 14) glld16(hh + idx * 1024 + lane * 16, (char*)Hr + idx * 1024);
    }
  }

  // ---- per-lane k0-invariant inverse-swizzled source pointers.
  //      LDS byte beta holds elem (real>>1) of its row, real = off^((row&7)<<4).
  //      Issues per wave per chunk: w0-9: 2, w10-11: 1.
  const char* rp[2];
#pragma unroll
  for (int r = 0; r < 2; ++r) {
    const int idx = w + 12 * r;
    rp[r] = nullptr;
    if (idx < NISS) {
      const int beta = idx * 1024 + lane * 16;
      if (beta < HT_LDS) {
        const int row = beta >> 7;
        const int real = (beta & 127) ^ ((row & 7) << 4);
        rp[r] = (const char*)(Htb + ((size_t)b * SS + row) * D3 + (real >> 1));
      } else {
        const int bb = beta - HT_LDS;
        const int row = bb >> 7;
        const int real = (bb & 127) ^ ((row & 7) << 4);
        rp[r] = (const char*)(Wb + (size_t)row * D3 + (real >> 1));
      }
    }
  }

  // ---- prologue: stage pairs 0 and 1 ----
#pragma unroll
  for (int pp = 0; pp < 2; ++pp)
#pragma unroll
    for (int kc = 0; kc < 2; ++kc)
#pragma unroll
      for (int r = 0; r < 2; ++r)
        if (rp[r])
          glld16(rp[r] + (size_t)128 * (2 * pp + kc),
                 (char*)Stg[pp] + kc * CH_B + (w + 12 * r) * 1024);

  f32x4 acc[3][5];
#pragma unroll
  for (int mt = 0; mt < 3; ++mt)
#pragma unroll
    for (int nt = 0; nt < 5; ++nt) acc[mt][nt] = (f32x4){0.f, 0.f, 0.f, 0.f};

  const f16x8 zro = {0, 0, 0, 0, 0, 0, 0, 0};

  for (int p = 0; p < NPH; ++p) {
    // drain pair-p loads (and Hr on phase 0); keep pair p+1 in flight.
    if (w < 10) VMW(4); else VMW(2);
    __builtin_amdgcn_s_barrier();   // all waves' pair-p loads visible
    __builtin_amdgcn_sched_barrier(0);

    // issue pair p+2 into buf[(p+2)%3] — overlaps this phase's compute.
    // Past the end it WRAPS (dead buffer, always-valid addrs, uniform vmcnt).
    {
      char* dst = (char*)Stg[(p + 2) % 3];
      int pn = p + 2;
      if (pn >= NPH) pn -= NPH;
#pragma unroll
      for (int kc = 0; kc < 2; ++kc)
#pragma unroll
        for (int r = 0; r < 2; ++r)
          if (rp[r])
            glld16(rp[r] + (size_t)128 * (2 * pn + kc),
                   dst + kc * CH_B + (w + 12 * r) * 1024);
    }

    // this wave computes only its K-half (kh) of the 128-K phase.
    const char* S = (const char*)Stg[p % 3] + kh * CH_B;
    const int k0 = (2 * p + kh) * 64;
#pragma unroll
    for (int kk = 0; kk < 2; ++kk) {
      const int ko = kk * 32 + q * 8;
      const int xb = (ko * 2) ^ ((lane & 7) << 4);  // swizzled byte off
      const f16x8 hv = *(const f16x8*)&Hr[iw * D3 + k0 + ko];
      f16x8 af[3];
#pragma unroll
      for (int mt = 0; mt < 3; ++mt) {
        const f16x8 s = *(const f16x8*)(S + (jh * 48 + mt * 16 + lm) * 128 + xb) + hv;
        af[mt] = __builtin_elementwise_max(s, zro);
      }
      f16x8 bfv[5];
#pragma unroll
      for (int nt = 0; nt < 5; ++nt)
        bfv[nt] = *(const f16x8*)(S + HT_LDS + (nt * 16 + lm) * 128 + xb);
      __builtin_amdgcn_s_setprio(1);
#pragma unroll
      for (int nt = 0; nt < 5; ++nt)
#pragma unroll
        for (int mt = 0; mt < 3; ++mt)
          acc[mt][nt] = __builtin_amdgcn_mfma_f32_16x16x32_f16(af[mt], bfv[nt], acc[mt][nt], 0, 0, 0);
      __builtin_amdgcn_s_setprio(0);
    }
    // retire all own ds_reads before arriving at the next barrier, so the
    // DMA overwrite of buf[p%3] (issued after barrier p+1) cannot race them.
    asm volatile("s_waitcnt lgkmcnt(0)" ::: "memory");
    __builtin_amdgcn_sched_barrier(0);
  }

  // ---- cross-wave kh reduction through the (now dead) Stg LDS. ----
  // __syncthreads drains this wave's DMAs (incl. wrap prefetches) and
  // barriers, so no stale glld16 can land in Stg after this point.
  __syncthreads();
  float* RED = (float*)&Stg[0][0];  // 6 pairs x 15 slots x 1024 B = 92160 B
  if (w & 1) {
#pragma unroll
    for (int mt = 0; mt < 3; ++mt)
#pragma unroll
      for (int nt = 0; nt < 5; ++nt)
        *(f32x4*)&RED[(((w >> 1) * 15 + mt * 5 + nt) << 8) + lane * 4] = acc[mt][nt];
  }
  __syncthreads();
  if (!(w & 1)) {
    // epilogue: C layout col=lm (c), row=q*4+r (j within 16-tile)
#pragma unroll
    for (int nt = 0; nt < 5; ++nt) {
      const int c = nt * 16 + lm;
      if (c < NC) {
        const float rb = relb[c];
        const int rr = c / 3, tg = c % 3;
#pragma unroll
        for (int mt = 0; mt < 3; ++mt) {
          const f32x4 oth = *(const f32x4*)&RED[(((w >> 1) * 15 + mt * 5 + nt) << 8) + lane * 4];
          const int j0 = jh * 48 + mt * 16 + q * 4;
          float* base = out + ((((size_t)b * TAG + tg) * RR + rr) * SS + i) * SS + j0;
          float4 o;
          o.x = acc[mt][nt][0] + oth[0] + rb;
          o.y = acc[mt][nt][1] + oth[1] + rb;
          o.z = acc[mt][nt][2] + oth[2] + rb;
          o.w = acc[mt][nt][3] + oth[3] + rb;
          *(float4*)base = o;
        }
      }
    }
  }
}

// ---------------------------------------------------------------------------
extern "C" void kernel_launch(void* const* d_in, const int* in_sizes, int n_in,
                              void* d_out, int out_size, void* d_ws, size_t ws_size,
                              hipStream_t stream) {
  const float* enc   = (const float*)d_in[0];  // [8,96,768]
  const float* rel   = (const float*)d_in[1];  // [24,8,768]
  const float* projW = (const float*)d_in[2];  // [1536,2304]
  const float* projb = (const float*)d_in[3];  // [2304]
  const float* relW  = (const float*)d_in[4];  // [2304,72]
  const float* relb  = (const float*)d_in[5];  // [72]
  float* out = (float*)d_out;                  // [8,3,24,96,96]

  uint16_t* Hh16 = (uint16_t*)d_ws;                       // 768*2304 f16 (+512 slack)
  uint16_t* Htf  = Hh16 + (size_t)DD * D3 + 512;          // 768*2304 f16
  uint16_t* Wb   = Htf + (size_t)DD * D3;                 // 96*2304 f16 (80 used)
  uint16_t* Tp   = Wb + (size_t)96 * D3;                  // 2304*1536 bf16
  uint16_t* Ab   = Tp + (size_t)D3 * 2 * DD;              // 768*768 bf16
  float* Pst = (float*)(Ab + (size_t)DD * DD);            // 8*8*96 f32 (unused now)
  float* SG = Pst + (size_t)BB * RSEQ * SS;               // 8*8*104 f32

  hipMemsetAsync(SG, 0, (size_t)BB * RSEQ * 104 * sizeof(float), stream);
  k_prepSG<<<128, 256, 0, stream>>>(enc, rel, SG);
  k_refR<<<908, 256, 0, stream>>>(SG, enc, rel, relW, Wb, projW, Tp, Ab);
  k_proj<<<dim3(6, 72), 256, 0, stream>>>(Ab, Tp, projb, Hh16, Htf);
  k_pairs<<<256, 768, 0, stream>>>(Hh16, Htf, Wb, relb, out);
}

// Round 16
// 161.377 us; speedup vs baseline: 1.2716x; 1.2716x over previous
//
#include <hip/hip_runtime.h>
#include <hip/hip_bf16.h>
#include <math.h>
#include <stdint.h>
#include <string.h>

#define BB 8
#define SS 96
#define DD 768
#define RR 24
#define RSEQ 8
#define TAG 3
#define D3 2304   // 3*D
#define NC 72     // R*TAG

typedef __attribute__((ext_vector_type(8))) short bf16x8;
typedef __attribute__((ext_vector_type(4))) float f32x4;
typedef _Float16 f16x8 __attribute__((ext_vector_type(8)));
typedef _Float16 f16x2 __attribute__((ext_vector_type(2)));

// async global->LDS, 16 B/lane; LDS dest = wave-uniform base + lane*16.
typedef __attribute__((address_space(3))) uint8_t lds_u8;
typedef const __attribute__((address_space(1))) uint8_t glb_u8;
static __device__ __forceinline__ void glld16(const void* g, void* l) {
  __builtin_amdgcn_global_load_lds((glb_u8*)g, (lds_u8*)l, 16, 0, 0);
}

#define VMW(N) asm volatile("s_waitcnt vmcnt(" #N ")" ::: "memory")

// round-half-up f32 pair -> packed bf16x2: add,add,v_perm = 3 VALU.
static __device__ inline uint32_t pkrhu(float lo, float hi) {
  uint32_t a, b;
  memcpy(&a, &lo, 4);
  memcpy(&b, &hi, 4);
  return __builtin_amdgcn_perm(b + 0x8000u, a + 0x8000u, 0x07060302u);
}
static __device__ inline uint32_t pkrne(float lo, float hi) {
  uint32_t a, b;
  memcpy(&a, &lo, 4);
  memcpy(&b, &hi, 4);
  a += 0x7FFFu + ((a >> 16) & 1u);
  b += 0x7FFFu + ((b >> 16) & 1u);
  return (a >> 16) | (b & 0xFFFF0000u);
}
// f32 pair -> packed f16x2 (v_cvt_f16_f32 x2 + pack)
static __device__ inline uint32_t pkf16(float lo, float hi) {
  union { f16x2 h; uint32_t u; } r;
  r.h[0] = (_Float16)lo;
  r.h[1] = (_Float16)hi;
  return r.u;
}
static __device__ inline uint16_t f16b(float v) {
  union { _Float16 h; uint16_t u; } r;
  r.h = (_Float16)v;
  return r.u;
}

// ---------------------------------------------------------------------------
// Kernel 0 (fused prep): blocks 0..35 = prepW (rel_W^T -> f16), 36..899 =
// proj_W transpose (bf16, feeds k_proj MFMA), 900..1027 = S0/G k-split
// partial dots (atomicAdd into pre-zeroed SG).
// ---------------------------------------------------------------------------
__global__ __launch_bounds__(256) void k_prep0(const float* __restrict__ relW,
                                               uint16_t* __restrict__ Wb,
                                               const float* __restrict__ projW,
                                               uint16_t* __restrict__ Tp,
                                               const float* __restrict__ enc,
                                               const float* __restrict__ rel,
                                               float* __restrict__ SG) {
  __shared__ __align__(16) char smem[24704];
  const int blk = blockIdx.x;
  const int t = threadIdx.x;

  if (blk < 36) {
    // ---- Wb[96][2304] f16 = rel_W^T (rows 72..79 zero; 80..95 untouched) ----
    float* tile = (float*)smem;  // 64*72 f32
    const int k0 = blk * 64;
    const float* src = relW + (size_t)k0 * NC;
    for (int e = t; e < 64 * NC / 4; e += 256) ((float4*)tile)[e] = ((const float4*)src)[e];
    __syncthreads();
    for (int u = t; u < 80 * 16; u += 256) {
      const int n = u >> 4, kq = (u & 15) * 4;
      uint2 w = {0u, 0u};
      if (n < NC) {
        w.x = pkf16(tile[(kq + 0) * NC + n], tile[(kq + 1) * NC + n]);
        w.y = pkf16(tile[(kq + 2) * NC + n], tile[(kq + 3) * NC + n]);
      }
      *(uint2*)&Wb[(size_t)n * D3 + k0 + kq] = w;
    }
  } else if (blk < 900) {
    // ---- Tp[2304][1536] bf16 = proj_W^T, 64x64 tile ----
    const int bx = blk - 36;
    float (*tile)[65] = (float(*)[65])smem;
    const int c0 = (bx % 36) * 64;
    const int r0 = (bx / 36) * 64;
    {
      const int tr = t >> 4;
      const int tc4 = (t & 15) * 4;
#pragma unroll
      for (int p = 0; p < 4; ++p) {
        const int r = tr + p * 16;
        const float4 v = *(const float4*)&projW[(size_t)(r0 + r) * D3 + c0 + tc4];
        tile[r][tc4 + 0] = v.x;
        tile[r][tc4 + 1] = v.y;
        tile[r][tc4 + 2] = v.z;
        tile[r][tc4 + 3] = v.w;
      }
    }
    __syncthreads();
    {
      const int cc = t >> 4;
      const int rr4 = (t & 15) * 4;
#pragma unroll
      for (int p = 0; p < 4; ++p) {
        const int c = cc + p * 16;
        uint2 w;
        w.x = pkrne(tile[rr4 + 0][c], tile[rr4 + 1][c]);
        w.y = pkrne(tile[rr4 + 2][c], tile[rr4 + 3][c]);
        *(uint2*)&Tp[(size_t)(c0 + c) * (2 * DD) + r0 + rr4] = w;
      }
    }
  } else {
    // ---- S0/G partial: sample b, d-chunk [d0, d0+48). ----
    const int idx = blk - 900;
    const int b = idx >> 4;
    const int d0 = (idx & 15) * 48;
    float (*AsF)[48] = (float(*)[48])smem;  // 8 x 48 f32 = 1.5 KB

    if (t < 96) {
      const int r = t / 12, q4 = (t % 12) * 4;
      *(float4*)&AsF[r][q4] = *(const float4*)&rel[((size_t)b * RSEQ + r) * DD + d0 + q4];
    }
    __syncthreads();

    for (int e = t; e < RSEQ * (SS + RSEQ); e += 256) {
      const int r = e & 7, s = e >> 3;
      const float* row = (s < SS) ? (enc + ((size_t)b * SS + s) * DD + d0) : &AsF[s - SS][0];
      float a0 = 0.f, a1 = 0.f, a2 = 0.f, a3 = 0.f;
#pragma unroll
      for (int d = 0; d < 48; d += 4) {
        const float4 rv = *(const float4*)&row[d];
        a0 += AsF[r][d + 0] * rv.x;
        a1 += AsF[r][d + 1] * rv.y;
        a2 += AsF[r][d + 2] * rv.z;
        a3 += AsF[r][d + 3] * rv.w;
      }
      atomicAdd(&SG[((size_t)b * RSEQ + r) * 104 + s], (a0 + a1) + (a2 + a3));
    }
  }
}

// ---------------------------------------------------------------------------
// Kernel 1a v7: refine serial core — 512 threads, WAVE w OWNS ROW w. G-row
// and S0 in registers; scores computed in-register from P (LDS); softmax is
// ONE 12-level shuffle chain per step (the 256-thread version serialized 2
// rows x 12 levels per wave = 24 dependent ~60cy cross-lane ops). Reduction
// order per row identical (same lane mapping, xor 32..1, same accumulation
// order) -> bit-identical results. Runs alone on 8 CUs — kept as a separate
// launch (fusing prep into it regressed 2x: LDS-pipe interference, round 15).
// grid 8 x 512.
// ---------------------------------------------------------------------------
__global__ __launch_bounds__(512) void k_refS(const float* __restrict__ SG,
                                              float* __restrict__ Pst) {
  const int b = blockIdx.x;
  const int t = threadIdx.x;
  const int w = t >> 6, l = t & 63;
  __shared__ float P[RSEQ][SS];
  const float scale = 0.036084391824351613f;  // 1/sqrt(768)
  const float* base = SG + (size_t)b * RSEQ * 104;

  float g[RSEQ];
#pragma unroll
  for (int r2 = 0; r2 < RSEQ; ++r2) g[r2] = base[w * 104 + 96 + r2];
  const float s0a = base[w * 104 + l];
  const float s0b = (l < 32) ? base[w * 104 + 64 + l] : 0.f;

  P[w][l] = 0.f;
  if (l < 32) P[w][64 + l] = 0.f;
  __syncthreads();

  for (int step = 0; step < RR; ++step) {
    // scores for row w from previous-step P (Jacobi)
    float p0[RSEQ], p1[RSEQ];
#pragma unroll
    for (int r2 = 0; r2 < RSEQ; ++r2) {
      p0[r2] = P[r2][l];
      p1[r2] = (l < 32) ? P[r2][64 + l] : 0.f;
    }
    float x0 = s0a, x1 = s0b;
#pragma unroll
    for (int r2 = 0; r2 < RSEQ; ++r2) {
      x0 += g[r2] * p0[r2];
      x1 += g[r2] * p1[r2];
    }
    x0 *= scale;
    x1 *= scale;
    float mx = fmaxf(x0, (l < 32) ? x1 : -1e30f);
#pragma unroll
    for (int o = 32; o > 0; o >>= 1) mx = fmaxf(mx, __shfl_xor(mx, o, 64));
    const float e0 = __expf(x0 - mx);
    const float e1 = (l < 32) ? __expf(x1 - mx) : 0.f;
    float sm = e0 + e1;
#pragma unroll
    for (int o = 32; o > 0; o >>= 1) sm += __shfl_xor(sm, o, 64);
    const float inv = 1.f / sm;
    __syncthreads();              // all waves done READING P
    P[w][l] += e0 * inv;
    if (l < 32) P[w][64 + l] += e1 * inv;
    __syncthreads();              // writes visible for next step
  }

  float* pb = Pst + (size_t)b * RSEQ * SS;
  pb[w * SS + l] = P[w][l];
  if (l < 32) pb[w * SS + 64 + l] = P[w][64 + l];
}

// ---------------------------------------------------------------------------
// Kernel 1b: refine epilogue: enc' bf16 = enc + P^T @ A. grid 96 (8 rows/blk).
// ---------------------------------------------------------------------------
__global__ __launch_bounds__(256) void k_refB(const float* __restrict__ enc,
                                              const float* __restrict__ rel,
                                              const float* __restrict__ Pst,
                                              uint16_t* __restrict__ encRb) {
  const int blk = blockIdx.x;
  const int b = blk / 12;
  const int s0 = (blk % 12) * 8;
  const int t = threadIdx.x;
  __shared__ float As[RSEQ][DD + 4];
  __shared__ float Pl[RSEQ][8];

  const float* Ag = rel + (size_t)b * RSEQ * DD;
  for (int e = t; e < RSEQ * DD / 4; e += 256) {
    const int r = (e * 4) / DD, d = (e * 4) % DD;
    *(float4*)&As[r][d] = *(const float4*)&Ag[e * 4];
  }
  if (t < RSEQ * 8) {
    const int r = t >> 3, sl = t & 7;
    Pl[r][sl] = Pst[(size_t)b * RSEQ * SS + r * SS + s0 + sl];
  }
  __syncthreads();

  const float* Eb = enc + ((size_t)b * SS + s0) * DD;
  uint16_t* Ob = encRb + ((size_t)b * SS + s0) * DD;
  for (int e = t; e < 8 * DD / 4; e += 256) {
    const int sl = (e * 4) / DD, d = (e * 4) % DD;
    float4 v = ((const float4*)Eb)[e];
#pragma unroll
    for (int r = 0; r < RSEQ; ++r) {
      const float p = Pl[r][sl];
      v.x += p * As[r][d + 0];
      v.y += p * As[r][d + 1];
      v.z += p * As[r][d + 2];
      v.w += p * As[r][d + 3];
    }
    uint2 w;
    w.x = pkrhu(v.x, v.y);
    w.y = pkrhu(v.z, v.w);
    *(uint2*)&Ob[e * 4] = w;
  }
}

// ---------------------------------------------------------------------------
// Kernel 2 v2: projection GEMM — 128x64 tiles: reads/MFMA 0.75, 432 blocks.
// glld16 2-barrier schedule. LDS 27648 B -> 4 blocks/CU. grid (6,72).
// ---------------------------------------------------------------------------
__global__ __launch_bounds__(256, 4) void k_proj(const uint16_t* __restrict__ Ab,
                                                 const uint16_t* __restrict__ Bt,
                                                 const float* __restrict__ pb,
                                                 uint16_t* __restrict__ Hh16,
                                                 uint16_t* __restrict__ Htf) {
  const int m0 = blockIdx.x * 128;
  const int gn0 = blockIdx.y * 64;
  const bool isH = gn0 < D3;               // uniform per block
  const int n0 = isH ? gn0 : gn0 - D3;
  const int halfk = isH ? 0 : DD;
  const int t = threadIdx.x, w = t >> 6, lane = t & 63;
  const int wm = w >> 1, wn = w & 1;
  const int lm = lane & 15, q = lane >> 4;

  __shared__ __align__(16) uint16_t As[128 * 72];  // 18432 B (18 issues)
  __shared__ __align__(16) uint16_t Bs[64 * 72];   //  9216 B (9 issues)

  const char* rp[7];
  char* lp[7];
#pragma unroll
  for (int r = 0; r < 7; ++r) {
    const int idx = w + 4 * r;
    rp[r] = nullptr;
    lp[r] = nullptr;
    if (idx < 27) {
      const int ii = (idx < 18) ? idx : idx - 18;
      const int beta = ii * 1024 + lane * 16;
      const int elem = beta >> 1;
      const int row = elem / 72;
      int o = elem - row * 72;
      if (o >= 64) o = 0;  // pad lanes: safe addr, land in LDS row pad
      if (idx < 18) {
        rp[r] = (const char*)(Ab + (size_t)(m0 + row) * DD + o);
        lp[r] = (char*)As + ii * 1024;
      } else {
        rp[r] = (const char*)(Bt + (size_t)(n0 + row) * (2 * DD) + halfk + o);
        lp[r] = (char*)Bs + ii * 1024;
      }
    }
  }

  f32x4 acc[4][2];
#pragma unroll
  for (int a = 0; a < 4; ++a)
#pragma unroll
    for (int c = 0; c < 2; ++c) acc[a][c] = (f32x4){0.f, 0.f, 0.f, 0.f};

  for (int k0 = 0; k0 < DD; k0 += 64) {
    __syncthreads();
#pragma unroll
    for (int r = 0; r < 7; ++r)
      if (rp[r]) glld16(rp[r] + 2 * k0, lp[r]);
    __syncthreads();
#pragma unroll
    for (int kk = 0; kk < 2; ++kk) {
      const int ko = kk * 32 + q * 8;
      bf16x8 af[4], bf[2];
#pragma unroll
      for (int mt = 0; mt < 4; ++mt)
        af[mt] = *(const bf16x8*)&As[(wm * 64 + mt * 16 + lm) * 72 + ko];
#pragma unroll
      for (int nt = 0; nt < 2; ++nt)
        bf[nt] = *(const bf16x8*)&Bs[(wn * 32 + nt * 16 + lm) * 72 + ko];
#pragma unroll
      for (int nt = 0; nt < 2; ++nt)
#pragma unroll
        for (int mt = 0; mt < 4; ++mt)
          acc[mt][nt] = __builtin_amdgcn_mfma_f32_16x16x32_bf16(af[mt], bf[nt], acc[mt][nt], 0, 0, 0);
    }
  }

#pragma unroll
  for (int nt = 0; nt < 2; ++nt) {
    const int ncol = n0 + wn * 32 + nt * 16 + lm;
    const int mrow = m0 + wm * 64 + q * 4;
    uint16_t* dst = isH ? Hh16 : Htf;
    const float bias = isH ? pb[ncol] : 0.f;
#pragma unroll
    for (int mt = 0; mt < 4; ++mt)
#pragma unroll
      for (int r = 0; r < 4; ++r)
        dst[(size_t)(mrow + mt * 16 + r) * D3 + ncol] = f16b(acc[mt][nt][r] + bias);
  }
}

// ---------------------------------------------------------------------------
// Kernel 3: pairwise GEMM v14 (frozen) — 12 waves = (iw x jh x kh); wave does
// full 48x80 tile of its i for its K=64 half of each 128-K phase; wave pairs
// reduce acc at the end through dead Stg. 3 pair-bufs, issue-after-barrier,
// counted vmcnt 4/2, XOR-swizzle, wrap prefetch, LDS 150528 -> 1 block/CU.
// grid 256, 768 threads.
// ---------------------------------------------------------------------------
#define HT_LDS 12288                     // 96 rows x 128 B
#define CH_B 22528                       // one chunk: 22 issues x 1024
#define NISS 22
#define NKC 36                           // K chunks of 64
#define NPH 18                           // phases of 2 chunks

__global__ __launch_bounds__(768, 1) void k_pairs(const uint16_t* __restrict__ Hh,
                                                  const uint16_t* __restrict__ Htb,
                                                  const uint16_t* __restrict__ Wb,
                                                  const float* __restrict__ relb,
                                                  float* __restrict__ out) {
  const int blk = blockIdx.x;
  const int b = blk >> 5, ii = blk & 31;
  const int t = threadIdx.x;
  const int w = t >> 6, lane = t & 63;
  const int lm = lane & 15, q = lane >> 4;
  const int iw = w >> 2;            // which of the 3 i's
  const int jh = (w >> 1) & 1;      // j-half (48 rows)
  const int kh = w & 1;             // K-half of each phase
  const int i = ii * 3 + iw;

  __shared__ __align__(16) uint16_t Hr[7680];             // 15360 B
  __shared__ __align__(16) uint16_t Stg[3][CH_B];         // 3 pair-bufs x 45056 B

  // ---- one-time: stage the 3 Hh rows (linear; issue idx 13 runs 512 B past
  //      the 3 rows — covered by Hh's slack) ----
  {
    const char* hh = (const char*)(Hh + ((size_t)b * SS + ii * 3) * D3);
#pragma unroll
    for (int r = 0; r < 2; ++r) {
      const int idx = w + 12 * r;
      if (idx < 14) glld16(hh + idx * 1024 + lane * 16, (char*)Hr + idx * 1024);
    }
  }

  // ---- per-lane k0-invariant inverse-swizzled source pointers.
  //      LDS byte beta holds elem (real>>1) of its row, real = off^((row&7)<<4).
  //      Issues per wave per chunk: w0-9: 2, w10-11: 1.
  const char* rp[2];
#pragma unroll
  for (int r = 0; r < 2; ++r) {
    const int idx = w + 12 * r;
    rp[r] = nullptr;
    if (idx < NISS) {
      const int beta = idx * 1024 + lane * 16;
      if (beta < HT_LDS) {
        const int row = beta >> 7;
        const int real = (beta & 127) ^ ((row & 7) << 4);
        rp[r] = (const char*)(Htb + ((size_t)b * SS + row) * D3 + (real >> 1));
      } else {
        const int bb = beta - HT_LDS;
        const int row = bb >> 7;
        const int real = (bb & 127) ^ ((row & 7) << 4);
        rp[r] = (const char*)(Wb + (size_t)row * D3 + (real >> 1));
      }
    }
  }

  // ---- prologue: stage pairs 0 and 1 ----
#pragma unroll
  for (int pp = 0; pp < 2; ++pp)
#pragma unroll
    for (int kc = 0; kc < 2; ++kc)
#pragma unroll
      for (int r = 0; r < 2; ++r)
        if (rp[r])
          glld16(rp[r] + (size_t)128 * (2 * pp + kc),
                 (char*)Stg[pp] + kc * CH_B + (w + 12 * r) * 1024);

  f32x4 acc[3][5];
#pragma unroll
  for (int mt = 0; mt < 3; ++mt)
#pragma unroll
    for (int nt = 0; nt < 5; ++nt) acc[mt][nt] = (f32x4){0.f, 0.f, 0.f, 0.f};

  const f16x8 zro = {0, 0, 0, 0, 0, 0, 0, 0};

  for (int p = 0; p < NPH; ++p) {
    // drain pair-p loads (and Hr on phase 0); keep pair p+1 in flight.
    if (w < 10) VMW(4); else VMW(2);
    __builtin_amdgcn_s_barrier();   // all waves' pair-p loads visible
    __builtin_amdgcn_sched_barrier(0);

    // issue pair p+2 into buf[(p+2)%3] — overlaps this phase's compute.
    // Past the end it WRAPS (dead buffer, always-valid addrs, uniform vmcnt).
    {
      char* dst = (char*)Stg[(p + 2) % 3];
      int pn = p + 2;
      if (pn >= NPH) pn -= NPH;
#pragma unroll
      for (int kc = 0; kc < 2; ++kc)
#pragma unroll
        for (int r = 0; r < 2; ++r)
          if (rp[r])
            glld16(rp[r] + (size_t)128 * (2 * pn + kc),
                   dst + kc * CH_B + (w + 12 * r) * 1024);
    }

    // this wave computes only its K-half (kh) of the 128-K phase.
    const char* S = (const char*)Stg[p % 3] + kh * CH_B;
    const int k0 = (2 * p + kh) * 64;
#pragma unroll
    for (int kk = 0; kk < 2; ++kk) {
      const int ko = kk * 32 + q * 8;
      const int xb = (ko * 2) ^ ((lane & 7) << 4);  // swizzled byte off
      const f16x8 hv = *(const f16x8*)&Hr[iw * D3 + k0 + ko];
      f16x8 af[3];
#pragma unroll
      for (int mt = 0; mt < 3; ++mt) {
        const f16x8 s = *(const f16x8*)(S + (jh * 48 + mt * 16 + lm) * 128 + xb) + hv;
        af[mt] = __builtin_elementwise_max(s, zro);
      }
      f16x8 bfv[5];
#pragma unroll
      for (int nt = 0; nt < 5; ++nt)
        bfv[nt] = *(const f16x8*)(S + HT_LDS + (nt * 16 + lm) * 128 + xb);
      __builtin_amdgcn_s_setprio(1);
#pragma unroll
      for (int nt = 0; nt < 5; ++nt)
#pragma unroll
        for (int mt = 0; mt < 3; ++mt)
          acc[mt][nt] = __builtin_amdgcn_mfma_f32_16x16x32_f16(af[mt], bfv[nt], acc[mt][nt], 0, 0, 0);
      __builtin_amdgcn_s_setprio(0);
    }
    // retire all own ds_reads before arriving at the next barrier, so the
    // DMA overwrite of buf[p%3] (issued after barrier p+1) cannot race them.
    asm volatile("s_waitcnt lgkmcnt(0)" ::: "memory");
    __builtin_amdgcn_sched_barrier(0);
  }

  // ---- cross-wave kh reduction through the (now dead) Stg LDS. ----
  // __syncthreads drains this wave's DMAs (incl. wrap prefetches) and
  // barriers, so no stale glld16 can land in Stg after this point.
  __syncthreads();
  float* RED = (float*)&Stg[0][0];  // 6 pairs x 15 slots x 1024 B = 92160 B
  if (w & 1) {
#pragma unroll
    for (int mt = 0; mt < 3; ++mt)
#pragma unroll
      for (int nt = 0; nt < 5; ++nt)
        *(f32x4*)&RED[(((w >> 1) * 15 + mt * 5 + nt) << 8) + lane * 4] = acc[mt][nt];
  }
  __syncthreads();
  if (!(w & 1)) {
    // epilogue: C layout col=lm (c), row=q*4+r (j within 16-tile)
#pragma unroll
    for (int nt = 0; nt < 5; ++nt) {
      const int c = nt * 16 + lm;
      if (c < NC) {
        const float rb = relb[c];
        const int rr = c / 3, tg = c % 3;
#pragma unroll
        for (int mt = 0; mt < 3; ++mt) {
          const f32x4 oth = *(const f32x4*)&RED[(((w >> 1) * 15 + mt * 5 + nt) << 8) + lane * 4];
          const int j0 = jh * 48 + mt * 16 + q * 4;
          float* base = out + ((((size_t)b * TAG + tg) * RR + rr) * SS + i) * SS + j0;
          float4 o;
          o.x = acc[mt][nt][0] + oth[0] + rb;
          o.y = acc[mt][nt][1] + oth[1] + rb;
          o.z = acc[mt][nt][2] + oth[2] + rb;
          o.w = acc[mt][nt][3] + oth[3] + rb;
          *(float4*)base = o;
        }
      }
    }
  }
}

// ---------------------------------------------------------------------------
extern "C" void kernel_launch(void* const* d_in, const int* in_sizes, int n_in,
                              void* d_out, int out_size, void* d_ws, size_t ws_size,
                              hipStream_t stream) {
  const float* enc   = (const float*)d_in[0];  // [8,96,768]
  const float* rel   = (const float*)d_in[1];  // [24,8,768]
  const float* projW = (const float*)d_in[2];  // [1536,2304]
  const float* projb = (const float*)d_in[3];  // [2304]
  const float* relW  = (const float*)d_in[4];  // [2304,72]
  const float* relb  = (const float*)d_in[5];  // [72]
  float* out = (float*)d_out;                  // [8,3,24,96,96]

  uint16_t* Hh16 = (uint16_t*)d_ws;                       // 768*2304 f16 (+512 slack)
  uint16_t* Htf  = Hh16 + (size_t)DD * D3 + 512;          // 768*2304 f16
  uint16_t* Wb   = Htf + (size_t)DD * D3;                 // 96*2304 f16 (80 used)
  uint16_t* Tp   = Wb + (size_t)96 * D3;                  // 2304*1536 bf16
  uint16_t* Ab   = Tp + (size_t)D3 * 2 * DD;              // 768*768 bf16
  float* Pst = (float*)(Ab + (size_t)DD * DD);            // 8*8*96 f32
  float* SG = Pst + (size_t)BB * RSEQ * SS;               // 8*8*104 f32

  hipMemsetAsync(SG, 0, (size_t)BB * RSEQ * 104 * sizeof(float), stream);
  k_prep0<<<1028, 256, 0, stream>>>(relW, Wb, projW, Tp, enc, rel, SG);
  k_refS<<<BB, 512, 0, stream>>>(SG, Pst);
  k_refB<<<96, 256, 0, stream>>>(enc, rel, Pst, Ab);
  k_proj<<<dim3(6, 72), 256, 0, stream>>>(Ab, Tp, projb, Hh16, Htf);
  k_pairs<<<256, 768, 0, stream>>>(Hh16, Htf, Wb, relb, out);
}